// Round 8
// baseline (674.240 us; speedup 1.0000x reference)
//
#include <hip/hip_runtime.h>
#include <hip/hip_bf16.h>
#include <cstdint>

// SpatialAttentionModule: x[4,256,64,64] fp32; q=Wq x, k=Wk x, v=Wv x (1x1 conv);
// energy = q^T k per batch (N=4096), softmax over j, out = gamma*(v@attn^T) + x.
//
// Round-8: barrier-free k_attn. R7's fat waves spilled (WRITE_SIZE 2.1 GB of
// scratch). Root problem of R2-R7: 16-q waves give exactly 1024 waves
// (1/SIMD) unless keys are split, and every per-tile __syncthreads drains the
// prefetch DMA (vmcnt(0)) so staging latency was never hidden.
// New structure: K is [key][ch] and V is [ch][key], so MFMA A-fragments are
// 16B-contiguous in GLOBAL memory -> feed MFMA straight from L1/L2. No LDS
// K/V staging, no DMA, no in-loop barriers. Block = 16 queries, 4 waves;
// wave w owns keys [w*1024,(w+1)*1024) with private online softmax (m,l,O);
// one end-of-kernel flash merge via LDS (m/l exchange + 3 rounds of 4KB
// channel-slice swaps). Grid 1024 -> 4096 independent waves (4/SIMD),
// VGPR ~150 -> 3 blocks/CU.
// MFMA 16x16x32 layouts (HW-verified m89/m91):
//   A[m=lane&15][k=quad*8+j], B[k=quad*8+j][n=lane&15], C/D: col=lane&15, row=quad*4+reg.

#define C_DIM 256
#define N_DIM 4096
#define B_DIM 4

typedef _Float16 f16;
typedef f16 f16x8 __attribute__((ext_vector_type(8)));
typedef f16 f16x4 __attribute__((ext_vector_type(4)));
typedef float f32x4 __attribute__((ext_vector_type(4)));

// ---------------- prep: transpose-cast x -> xs fp16 [B*N][256] ----------------
__global__ __launch_bounds__(256) void k_prep_xs(const float* __restrict__ x,
                                                 f16* __restrict__ xs) {
  __shared__ float tile[64][65];
  const int b = blockIdx.z, nb = blockIdx.x * 64, cb = blockIdx.y * 64;
  const float* xb = x + (size_t)b * C_DIM * N_DIM;
  for (int i = threadIdx.x; i < 64 * 64; i += 256) {
    int c = i >> 6, n = i & 63;
    tile[c][n] = xb[(size_t)(cb + c) * N_DIM + nb + n];
  }
  __syncthreads();
  f16* xsb = xs + (size_t)b * N_DIM * C_DIM;
  for (int i = threadIdx.x; i < 64 * 64; i += 256) {
    int n = i >> 6, c = i & 63;
    xsb[(size_t)(nb + n) * C_DIM + cb + c] = (f16)tile[c][n];
  }
}

// ---------------- prep: cast 3 weight matrices -> fp16 [3*256][256] ----------------
__global__ __launch_bounds__(256) void k_cast_w(const float* __restrict__ Wq,
                                                const float* __restrict__ Wk,
                                                const float* __restrict__ Wv,
                                                f16* __restrict__ Wh) {
  int i = blockIdx.x * 256 + threadIdx.x;
  int sel = i >> 16, j = i & 65535;
  const float* s = (sel == 0) ? Wq : (sel == 1) ? Wk : Wv;
  Wh[i] = (f16)s[j];
}

// ---------------- QKV projection GEMMs (fp16, K=256) ----------------
// grid (512, 3). z<2: block = 32 g-rows; wave: gh=w>>1 (16 rows), oh=w&1
// (8 of 16 output tiles). z=2: wave: j-tile t = bx*2 + (w>>1), oh = w&1.
__global__ __launch_bounds__(256) void k_proj(const f16* __restrict__ xs,
                                              const f16* __restrict__ Wh,
                                              const float* __restrict__ bq,
                                              const float* __restrict__ bk,
                                              const float* __restrict__ bv,
                                              f16* __restrict__ Qh,
                                              f16* __restrict__ Kh,
                                              f16* __restrict__ Vh) {
  const int z = blockIdx.y;
  const int w = threadIdx.x >> 6, lane = threadIdx.x & 63;
  const int quad = lane >> 4, li = lane & 15;
  const int oh = w & 1;
  const f16* W = Wh + (size_t)z * 65536;
  const float* bias = (z == 0) ? bq : (z == 1) ? bk : bv;

  if (z < 2) {
    f16* out = (z == 0) ? Qh : Kh;
    const int g0 = blockIdx.x * 32 + (w >> 1) * 16;
    f16x8 a[8];
    const f16* arow = xs + (size_t)(g0 + li) * C_DIM + quad * 8;
#pragma unroll
    for (int kf = 0; kf < 8; kf++) a[kf] = *(const f16x8*)(arow + kf * 32);
    for (int ot = oh * 8; ot < oh * 8 + 8; ot++) {
      f32x4 acc = {0.f, 0.f, 0.f, 0.f};
      const f16* brow = W + (size_t)(ot * 16 + li) * C_DIM + quad * 8;
#pragma unroll
      for (int kf = 0; kf < 8; kf++) {
        f16x8 bf = *(const f16x8*)(brow + kf * 32);
        acc = __builtin_amdgcn_mfma_f32_16x16x32_f16(a[kf], bf, acc, 0, 0, 0);
      }
      float bb = bias[ot * 16 + li];
      f16* orow = out + (size_t)g0 * C_DIM + ot * 16 + li;
#pragma unroll
      for (int r = 0; r < 4; r++)
        orow[(size_t)(quad * 4 + r) * C_DIM] = (f16)(acc[r] + bb);
    }
  } else {
    const int t = blockIdx.x * 2 + (w >> 1);
    const int b = t >> 8, j0 = (t & 255) * 16;
    f16x8 bfr[8];
    const f16* brow = xs + (size_t)(b * N_DIM + j0 + li) * C_DIM + quad * 8;
#pragma unroll
    for (int kf = 0; kf < 8; kf++) bfr[kf] = *(const f16x8*)(brow + kf * 32);
    for (int ot = oh * 8; ot < oh * 8 + 8; ot++) {
      f32x4 acc = {0.f, 0.f, 0.f, 0.f};
      const f16* arow = W + (size_t)(ot * 16 + li) * C_DIM + quad * 8;
#pragma unroll
      for (int kf = 0; kf < 8; kf++) {
        f16x8 af = *(const f16x8*)(arow + kf * 32);
        acc = __builtin_amdgcn_mfma_f32_16x16x32_f16(af, bfr[kf], acc, 0, 0, 0);
      }
      f16* obase = Vh + ((size_t)(b * C_DIM + ot * 16 + quad * 4)) * N_DIM + j0 + li;
#pragma unroll
      for (int r = 0; r < 4; r++) {
        float bb = bias[ot * 16 + quad * 4 + r];
        obase[(size_t)r * N_DIM] = (f16)(acc[r] + bb);
      }
    }
  }
}

// ---------------- fused attention: barrier-free, direct-global fragments ----------------
// grid (256, 4): 16-query block, batch; 4 waves; wave w owns keys
// [w*1024, (w+1)*1024) as 32 tiles of 32 keys. No in-loop barriers.
// LDS: P per wave [16 q][PSTR=40] f16; merge: mx 2x64 floats + buf 4x4KB.
#define PSTR 40
#define P_LDS_F16 (4 * 16 * PSTR)              // 2560 f16 = 5120 B
#define MX_OFF P_LDS_F16                        // 128 floats (m then l): 512 B
#define BUF_OFF (P_LDS_F16 + 256)               // f16 units; 16 KB float buf
#define SMEM_F16 (P_LDS_F16 + 256 + 8192)       // 5120 + 512 + 16384 = 22016 B

__global__ __launch_bounds__(256, 3) void k_attn(const f16* __restrict__ Qh,
                                                 const f16* __restrict__ Kh,
                                                 const f16* __restrict__ Vh,
                                                 const float* __restrict__ x,
                                                 const float* __restrict__ gamma_p,
                                                 float* __restrict__ out) {
  __shared__ __align__(16) f16 smem[SMEM_F16];
  const int b = blockIdx.y;
  const int tid = threadIdx.x;
  const int w = tid >> 6, lane = tid & 63;
  const int quad = lane >> 4, li = lane & 15;
  const int q0 = blockIdx.x * 16;

  const f16* Kb = Kh + (size_t)b * N_DIM * C_DIM;
  const f16* Vb = Vh + (size_t)b * C_DIM * N_DIM;
  f16* Pw = smem + w * 16 * PSTR;
  float* mx = (float*)(smem + MX_OFF);
  float* buf = (float*)(smem + BUF_OFF);

  // Q B-frags (n = query col li, k = channel): read once
  f16x8 qf[8];
  {
    const f16* qrow = Qh + (size_t)(b * N_DIM + q0 + li) * C_DIM + quad * 8;
#pragma unroll
    for (int kf = 0; kf < 8; kf++) qf[kf] = *(const f16x8*)(qrow + kf * 32);
  }

  float m = -3.0e38f, l = 0.0f;
  f32x4 acc[16];
#pragma unroll
  for (int ct = 0; ct < 16; ct++) acc[ct] = (f32x4){0.f, 0.f, 0.f, 0.f};

  const int kt0 = w * 1024;           // this wave's private key range
  for (int t = 0; t < 32; t++) {
    const int keybase = kt0 + t * 32;

    // ---- S: 32 keys x 16 queries, K frags direct from global ----
    // A-frag: lane reads K[keybase + sub*16 + li][quad*8 + kf*32 .. +8] (16B)
    f32x4 s[2];
#pragma unroll
    for (int sub = 0; sub < 2; sub++) {
      const f16* ka = Kb + (size_t)(keybase + sub * 16 + li) * C_DIM + quad * 8;
      f32x4 ss = {0.f, 0.f, 0.f, 0.f};
#pragma unroll
      for (int kf = 0; kf < 8; kf++) {
        f16x8 kfr = *(const f16x8*)(ka + kf * 32);
        ss = __builtin_amdgcn_mfma_f32_16x16x32_f16(kfr, qf[kf], ss, 0, 0, 0);
      }
      s[sub] = ss;
    }

    // ---- in-wave online softmax (per query col li) ----
    float tm = fmaxf(fmaxf(fmaxf(s[0][0], s[0][1]), fmaxf(s[0][2], s[0][3])),
                     fmaxf(fmaxf(s[1][0], s[1][1]), fmaxf(s[1][2], s[1][3])));
    tm = fmaxf(tm, __shfl_xor(tm, 16));
    tm = fmaxf(tm, __shfl_xor(tm, 32));
    float nm = fmaxf(m, tm);
    float al = __expf(m - nm);
    bool upd = nm > m;
    m = nm;
    if (__any(upd)) {
      l *= al;
#pragma unroll
      for (int ct = 0; ct < 16; ct++) acc[ct] *= al;
    }
#pragma unroll
    for (int sub = 0; sub < 2; sub++) {
      float p0 = __expf(s[sub][0] - m);
      float p1 = __expf(s[sub][1] - m);
      float p2 = __expf(s[sub][2] - m);
      float p3 = __expf(s[sub][3] - m);
      l += (p0 + p1) + (p2 + p3);
      *(f16x4*)(Pw + li * PSTR + sub * 16 + quad * 4) =
          (f16x4){(f16)p0, (f16)p1, (f16)p2, (f16)p3};
    }

    // ---- PV: V frags direct from global; P B-frag from per-wave LDS ----
    f16x8 pf = *(const f16x8*)(Pw + li * PSTR + quad * 8);   // keys quad*8..+8
#pragma unroll
    for (int ct = 0; ct < 16; ct++) {
      const f16* va = Vb + (size_t)(ct * 16 + li) * N_DIM + keybase + quad * 8;
      f16x8 vf = *(const f16x8*)(va);
      acc[ct] = __builtin_amdgcn_mfma_f32_16x16x32_f16(vf, pf, acc[ct], 0, 0, 0);
    }
  }

  // ---- flash merge across the 4 key-range waves ----
  l += __shfl_xor(l, 16);
  l += __shfl_xor(l, 32);             // l per query col (all lanes)
  if (lane < 16) {
    mx[w * 16 + lane] = m;
    mx[64 + w * 16 + lane] = l;
  }
  __syncthreads();
  float mg = fmaxf(fmaxf(mx[0 + li], mx[16 + li]), fmaxf(mx[32 + li], mx[48 + li]));
  float lg = __expf(mx[0 + li] - mg) * mx[64 + li] +
             __expf(mx[16 + li] - mg) * mx[80 + li] +
             __expf(mx[32 + li] - mg) * mx[96 + li] +
             __expf(mx[48 + li] - mg) * mx[112 + li];
  float aw = __expf(m - mg);
#pragma unroll
  for (int ct = 0; ct < 16; ct++) acc[ct] *= aw;

  // 3 rounds: send rescaled channel slices to partner waves, accumulate own.
#pragma unroll
  for (int r = 1; r < 4; r++) {
    const int dest = (w + r) & 3;
    __syncthreads();                  // slots free from previous round
#pragma unroll
    for (int cl = 0; cl < 4; cl++) {
      int ct = dest * 4 + cl;
#pragma unroll
      for (int rr = 0; rr < 4; rr++)
        buf[dest * 1024 + (cl * 16 + quad * 4 + rr) * 16 + li] = acc[ct][rr];
    }
    __syncthreads();
#pragma unroll
    for (int cl = 0; cl < 4; cl++) {
      int ct = w * 4 + cl;
#pragma unroll
      for (int rr = 0; rr < 4; rr++)
        acc[ct][rr] += buf[w * 1024 + (cl * 16 + quad * 4 + rr) * 16 + li];
    }
  }

  const float scale = gamma_p[0] / lg;
  const float* xb = x + (size_t)b * C_DIM * N_DIM;
  float* ob = out + (size_t)b * C_DIM * N_DIM;
#pragma unroll
  for (int cl = 0; cl < 4; cl++) {
    int ct = w * 4 + cl;
#pragma unroll
    for (int rr = 0; rr < 4; rr++) {
      int ch = ct * 16 + quad * 4 + rr;
      size_t off = (size_t)ch * N_DIM + q0 + li;
      ob[off] = acc[ct][rr] * scale + xb[off];
    }
  }
}

extern "C" void kernel_launch(void* const* d_in, const int* in_sizes, int n_in,
                              void* d_out, int out_size, void* d_ws, size_t ws_size,
                              hipStream_t stream) {
  const float* x     = (const float*)d_in[0];
  const float* Wq    = (const float*)d_in[1];
  const float* bq    = (const float*)d_in[2];
  const float* Wk    = (const float*)d_in[3];
  const float* bk    = (const float*)d_in[4];
  const float* Wv    = (const float*)d_in[5];
  const float* bv    = (const float*)d_in[6];
  const float* gamma = (const float*)d_in[7];
  float* out = (float*)d_out;

  // workspace: xs 8MB | Qh 8MB | Kh 8MB | Vh 8MB | Wh 384KB  (~32.4 MB)
  char* ws = (char*)d_ws;
  f16* xs = (f16*)(ws);
  f16* Qh = (f16*)(ws + (size_t)8  * 1024 * 1024);
  f16* Kh = (f16*)(ws + (size_t)16 * 1024 * 1024);
  f16* Vh = (f16*)(ws + (size_t)24 * 1024 * 1024);
  f16* Wh = (f16*)(ws + (size_t)32 * 1024 * 1024);

  k_prep_xs<<<dim3(64, 4, 4), 256, 0, stream>>>(x, xs);
  k_cast_w<<<dim3(768), 256, 0, stream>>>(Wq, Wk, Wv, Wh);
  k_proj<<<dim3(512, 3), 256, 0, stream>>>(xs, Wh, bq, bk, bv, Qh, Kh, Vh);
  k_attn<<<dim3(256, 4), 256, 0, stream>>>(Qh, Kh, Vh, x, gamma, out);
}